// Round 15
// baseline (274.180 us; speedup 1.0000x reference)
//
#include <hip/hip_runtime.h>
#include <hip/hip_fp16.h>

#define NGRAPH 256
#define FIN 64
#define HID 32
#define NB_SHIFT 8            // 256 nodes per bucket
#define NB_NODES 256
#define KMAX2 512
#define EPB 2048              // edges per partition block
#define EPT 8                 // edges per thread (256 threads)
#define NT 64                 // nodes per GEMM block
#define XPAD 65               // 64 + 1 pad (floats) per staged x row
#define HPAD 33               // 32 + 1 pad
#define PCAP 6016             // partC2 LDS edge-staging capacity

// A is stored as TWO half-tables of [N][16] fp16 (32 B rows, 3.2 MB each —
// each fits a 4 MB per-XCD L2). Table t holds features [16t, 16t+16).

// ---------- node GEMM 1: 64 nodes/block, thread = 2 nodes x 4 features ----------
__global__ __launch_bounds__(256, 4) void node_lin64(
    const float* __restrict__ x, const float* __restrict__ Wrel,
    const float* __restrict__ Wroot, const float* __restrict__ bias,
    __half* __restrict__ A, float* __restrict__ B, int N)
{
    __shared__ float sWr[FIN * HID];      // [k][f], 8 KB
    __shared__ float sWo[FIN * HID];      // 8 KB
    __shared__ float sb[HID];
    __shared__ float sx[NT * XPAD];       // 16.6 KB
    int tid = threadIdx.x;
    {
        const float4* Wr4 = (const float4*)Wrel;
        const float4* Wo4 = (const float4*)Wroot;
        for (int i = tid; i < FIN * HID / 4; i += 256) {
            ((float4*)sWr)[i] = Wr4[i];
            ((float4*)sWo)[i] = Wo4[i];
        }
        if (tid < HID) sb[tid] = bias[tid];
    }
    int base = blockIdx.x * NT;
    {
        const float4* x4 = (const float4*)x;
        for (int i = tid; i < NT * 16; i += 256) {
            int row = i >> 4, c4 = i & 15;
            int n = base + row;
            float4 v = (n < N) ? x4[(size_t)n * 16 + c4]
                               : make_float4(0.f, 0.f, 0.f, 0.f);
            *(float4*)&sx[row * XPAD + c4 * 4] = v;
        }
    }
    __syncthreads();

    int nl = tid >> 3;          // 0..31
    int fq = (tid & 7) * 4;     // feature quad base
    const float* xa = &sx[nl * XPAD];
    const float* xb = &sx[(nl + 32) * XPAD];
    float4 ar0 = make_float4(0.f,0.f,0.f,0.f), ao0 = ar0;
    float4 ar1 = ar0, ao1 = ar0;
    #pragma unroll 4
    for (int k = 0; k < FIN; ++k) {
        float4 w4 = *(const float4*)&sWr[k * HID + fq];
        float4 o4 = *(const float4*)&sWo[k * HID + fq];
        float va = xa[k], vb = xb[k];
        ar0.x = fmaf(va, w4.x, ar0.x); ar0.y = fmaf(va, w4.y, ar0.y);
        ar0.z = fmaf(va, w4.z, ar0.z); ar0.w = fmaf(va, w4.w, ar0.w);
        ao0.x = fmaf(va, o4.x, ao0.x); ao0.y = fmaf(va, o4.y, ao0.y);
        ao0.z = fmaf(va, o4.z, ao0.z); ao0.w = fmaf(va, o4.w, ao0.w);
        ar1.x = fmaf(vb, w4.x, ar1.x); ar1.y = fmaf(vb, w4.y, ar1.y);
        ar1.z = fmaf(vb, w4.z, ar1.z); ar1.w = fmaf(vb, w4.w, ar1.w);
        ao1.x = fmaf(vb, o4.x, ao1.x); ao1.y = fmaf(vb, o4.y, ao1.y);
        ao1.z = fmaf(vb, o4.z, ao1.z); ao1.w = fmaf(vb, o4.w, ao1.w);
    }
    float4 bb = *(const float4*)&sb[fq];
    size_t tOff = (fq < 16) ? (size_t)0 : (size_t)N * 16;
    int fl = fq & 15;
    int n0 = base + nl, n1 = base + nl + 32;
    if (n0 < N) {
        __half2 pa = __floats2half2_rn(ar0.x, ar0.y);
        __half2 pb = __floats2half2_rn(ar0.z, ar0.w);
        uint2 pk; pk.x = *(unsigned*)&pa; pk.y = *(unsigned*)&pb;
        *(uint2*)&A[tOff + (size_t)n0 * 16 + fl] = pk;
        ao0.x += bb.x; ao0.y += bb.y; ao0.z += bb.z; ao0.w += bb.w;
        *(float4*)&B[(size_t)n0 * HID + fq] = ao0;
    }
    if (n1 < N) {
        __half2 pa = __floats2half2_rn(ar1.x, ar1.y);
        __half2 pb = __floats2half2_rn(ar1.z, ar1.w);
        uint2 pk; pk.x = *(unsigned*)&pa; pk.y = *(unsigned*)&pb;
        *(uint2*)&A[tOff + (size_t)n1 * 16 + fl] = pk;
        ao1.x += bb.x; ao1.y += bb.y; ao1.z += bb.z; ao1.w += bb.w;
        *(float4*)&B[(size_t)n1 * HID + fq] = ao1;
    }
}

// ---------- node GEMM 2: relu fused on load, FIN=32 ----------
__global__ __launch_bounds__(256, 4) void node_lin32(
    const float* __restrict__ Hpre, const float* __restrict__ Wrel,
    const float* __restrict__ Wroot, const float* __restrict__ bias,
    __half* __restrict__ A, float* __restrict__ C, int N)
{
    __shared__ float sWr[HID * HID];      // 4 KB
    __shared__ float sWo[HID * HID];
    __shared__ float sb[HID];
    __shared__ float sh[NT * HPAD];       // 8.4 KB
    int tid = threadIdx.x;
    {
        const float4* Wr4 = (const float4*)Wrel;
        const float4* Wo4 = (const float4*)Wroot;
        for (int i = tid; i < HID * HID / 4; i += 256) {
            ((float4*)sWr)[i] = Wr4[i];
            ((float4*)sWo)[i] = Wo4[i];
        }
        if (tid < HID) sb[tid] = bias[tid];
    }
    int base = blockIdx.x * NT;
    {
        const float4* H4 = (const float4*)Hpre;
        for (int i = tid; i < NT * 8; i += 256) {
            int row = i >> 3, c4 = i & 7;
            int n = base + row;
            float4 v = make_float4(0.f, 0.f, 0.f, 0.f);
            if (n < N) {
                v = H4[(size_t)n * 8 + c4];
                v.x = v.x > 0.f ? v.x : 0.f; v.y = v.y > 0.f ? v.y : 0.f;
                v.z = v.z > 0.f ? v.z : 0.f; v.w = v.w > 0.f ? v.w : 0.f;
            }
            *(float4*)&sh[row * HPAD + c4 * 4] = v;
        }
    }
    __syncthreads();

    int nl = tid >> 3;
    int fq = (tid & 7) * 4;
    const float* xa = &sh[nl * HPAD];
    const float* xb = &sh[(nl + 32) * HPAD];
    float4 ar0 = make_float4(0.f,0.f,0.f,0.f), ao0 = ar0;
    float4 ar1 = ar0, ao1 = ar0;
    #pragma unroll 4
    for (int k = 0; k < HID; ++k) {
        float4 w4 = *(const float4*)&sWr[k * HID + fq];
        float4 o4 = *(const float4*)&sWo[k * HID + fq];
        float va = xa[k], vb = xb[k];
        ar0.x = fmaf(va, w4.x, ar0.x); ar0.y = fmaf(va, w4.y, ar0.y);
        ar0.z = fmaf(va, w4.z, ar0.z); ar0.w = fmaf(va, w4.w, ar0.w);
        ao0.x = fmaf(va, o4.x, ao0.x); ao0.y = fmaf(va, o4.y, ao0.y);
        ao0.z = fmaf(va, o4.z, ao0.z); ao0.w = fmaf(va, o4.w, ao0.w);
        ar1.x = fmaf(vb, w4.x, ar1.x); ar1.y = fmaf(vb, w4.y, ar1.y);
        ar1.z = fmaf(vb, w4.z, ar1.z); ar1.w = fmaf(vb, w4.w, ar1.w);
        ao1.x = fmaf(vb, o4.x, ao1.x); ao1.y = fmaf(vb, o4.y, ao1.y);
        ao1.z = fmaf(vb, o4.z, ao1.z); ao1.w = fmaf(vb, o4.w, ao1.w);
    }
    float4 bb = *(const float4*)&sb[fq];
    size_t tOff = (fq < 16) ? (size_t)0 : (size_t)N * 16;
    int fl = fq & 15;
    int n0 = base + nl, n1 = base + nl + 32;
    if (n0 < N) {
        __half2 pa = __floats2half2_rn(ar0.x, ar0.y);
        __half2 pb = __floats2half2_rn(ar0.z, ar0.w);
        uint2 pk; pk.x = *(unsigned*)&pa; pk.y = *(unsigned*)&pb;
        *(uint2*)&A[tOff + (size_t)n0 * 16 + fl] = pk;
        ao0.x += bb.x; ao0.y += bb.y; ao0.z += bb.z; ao0.w += bb.w;
        *(float4*)&C[(size_t)n0 * HID + fq] = ao0;
    }
    if (n1 < N) {
        __half2 pa = __floats2half2_rn(ar1.x, ar1.y);
        __half2 pb = __floats2half2_rn(ar1.z, ar1.w);
        uint2 pk; pk.x = *(unsigned*)&pa; pk.y = *(unsigned*)&pb;
        *(uint2*)&A[tOff + (size_t)n1 * 16 + fl] = pk;
        ao1.x += bb.x; ao1.y += bb.y; ao1.z += bb.z; ao1.w += bb.w;
        *(float4*)&C[(size_t)n1 * HID + fq] = ao1;
    }
}

// ---------- deterministic two-level partition build (no global atomics) ----------

__global__ __launch_bounds__(256) void bucket_hist(
    const int* __restrict__ dst, int* __restrict__ cbb, int E, int K, int NBLK)
{
    __shared__ int h[KMAX2];
    int tid = threadIdx.x;
    for (int i = tid; i < K; i += 256) h[i] = 0;
    __syncthreads();
    int e0 = blockIdx.x * EPB + tid * 8;
    if (e0 + 7 < E) {
        int4 d0 = *reinterpret_cast<const int4*>(dst + e0);
        int4 d1 = *reinterpret_cast<const int4*>(dst + e0 + 4);
        atomicAdd(&h[d0.x >> NB_SHIFT], 1); atomicAdd(&h[d0.y >> NB_SHIFT], 1);
        atomicAdd(&h[d0.z >> NB_SHIFT], 1); atomicAdd(&h[d0.w >> NB_SHIFT], 1);
        atomicAdd(&h[d1.x >> NB_SHIFT], 1); atomicAdd(&h[d1.y >> NB_SHIFT], 1);
        atomicAdd(&h[d1.z >> NB_SHIFT], 1); atomicAdd(&h[d1.w >> NB_SHIFT], 1);
    } else {
        for (int e = e0; e < E && e < e0 + 8; ++e)
            atomicAdd(&h[dst[e] >> NB_SHIFT], 1);
    }
    __syncthreads();
    for (int i = tid; i < K; i += 256)
        cbb[(size_t)i * NBLK + blockIdx.x] = h[i];
}

__global__ __launch_bounds__(256) void bucket_scan(
    int* __restrict__ cbb, int* __restrict__ btot, int NBLK)
{
    __shared__ int sc[256];
    size_t row = (size_t)blockIdx.x * NBLK;
    int t = threadIdx.x;
    int base = t * 4;
    int v[4]; int s = 0;
    #pragma unroll
    for (int j = 0; j < 4; ++j) { v[j] = (base + j < NBLK) ? cbb[row + base + j] : 0; s += v[j]; }
    sc[t] = s;
    __syncthreads();
    int acc = s;
    for (int off = 1; off < 256; off <<= 1) {
        int add = (t >= off) ? sc[t - off] : 0;
        __syncthreads();
        acc += add;
        sc[t] = acc;
        __syncthreads();
    }
    int run = acc - s;
    #pragma unroll
    for (int j = 0; j < 4; ++j) {
        if (base + j < NBLK) cbb[row + base + j] = run;
        run += v[j];
    }
    if (t == 255) btot[blockIdx.x] = acc;
}

__global__ __launch_bounds__(256) void btot_scan(
    const int* __restrict__ btot, int* __restrict__ bbase, int K)
{
    __shared__ int sc[256];
    int t = threadIdx.x;
    int base = t * 4;
    int v[4]; int s = 0;
    #pragma unroll
    for (int j = 0; j < 4; ++j) { v[j] = (base + j < K) ? btot[base + j] : 0; s += v[j]; }
    sc[t] = s;
    __syncthreads();
    int acc = s;
    for (int off = 1; off < 256; off <<= 1) {
        int add = (t >= off) ? sc[t - off] : 0;
        __syncthreads();
        acc += add;
        sc[t] = acc;
        __syncthreads();
    }
    int run = acc - s;
    #pragma unroll
    for (int j = 0; j < 4; ++j) {
        if (base + j < K) bbase[base + j] = run;
        run += v[j];
    }
    if (t == 255) bbase[K] = acc;
}

// partition: edges -> bucket-grouped staging; payload = {src | dloc<<17, ew}
__global__ __launch_bounds__(256) void partB(
    const int* __restrict__ src, const int* __restrict__ dst,
    const float* __restrict__ ew, const int* __restrict__ cbb,
    const int* __restrict__ bbase, int2* __restrict__ stg8,
    int E, int K, int NBLK)
{
    __shared__ int4 pay[EPB];       // 32 KB: {meta, ew, tgt, pad}
    __shared__ int h[KMAX2];
    __shared__ int lofs[KMAX2];
    __shared__ int gb[KMAX2];
    __shared__ int sc[256];
    int tid = threadIdx.x;
    for (int i = tid; i < K; i += 256) h[i] = 0;
    __syncthreads();

    int base = blockIdx.x * EPB;
    int es[EPT], ds[EPT]; float wsr[EPT];
    #pragma unroll
    for (int k = 0; k < EPT; ++k) {
        int e = base + k * 256 + tid;
        if (e < E) {
            es[k] = src[e]; ds[k] = dst[e]; wsr[k] = ew[e];
            atomicAdd(&h[ds[k] >> NB_SHIFT], 1);
        } else ds[k] = -1;
    }
    __syncthreads();

    int b0 = tid * 2;
    int v0 = (b0 < K) ? h[b0] : 0;
    int v1 = (b0 + 1 < K) ? h[b0 + 1] : 0;
    int s = v0 + v1;
    sc[tid] = s;
    __syncthreads();
    int acc = s;
    for (int off = 1; off < 256; off <<= 1) {
        int add = (tid >= off) ? sc[tid - off] : 0;
        __syncthreads();
        acc += add;
        sc[tid] = acc;
        __syncthreads();
    }
    int run = acc - s;
    if (b0 < K) lofs[b0] = run;
    if (b0 + 1 < K) lofs[b0 + 1] = run + v0;
    __syncthreads();

    for (int b = tid; b < K; b += 256) {
        gb[b] = bbase[b] + cbb[(size_t)b * NBLK + blockIdx.x];
        h[b] = lofs[b];
    }
    __syncthreads();

    #pragma unroll
    for (int k = 0; k < EPT; ++k) {
        if (ds[k] >= 0) {
            int b = ds[k] >> NB_SHIFT;
            int dloc = ds[k] & (NB_NODES - 1);
            int slot = atomicAdd(&h[b], 1);
            pay[slot] = make_int4(es[k] | (dloc << 17), __float_as_int(wsr[k]),
                                  gb[b] + slot - lofs[b], 0);
        }
    }
    __syncthreads();

    int tot = E - base; if (tot > EPB) tot = EPB;
    for (int i = tid; i < tot; i += 256) {
        int4 p = pay[i];
        stg8[p.z] = make_int2(p.x, p.y);
    }
}

// per bucket: counting-sort edges by dst node, LDS-staged single-pass
__global__ __launch_bounds__(512) void partC2(
    const int2* __restrict__ stg8, const int* __restrict__ bbase,
    int* __restrict__ rowptr, int2* __restrict__ perm, int N, int K)
{
    __shared__ int2 pe[PCAP];          // 47 KB edge staging
    __shared__ int hcnt[NB_NODES];
    __shared__ int hinc[NB_NODES];
    int b = blockIdx.x;
    int n0 = b << NB_SHIFT;
    int nTop = n0 + NB_NODES; if (nTop > N) nTop = N;
    int nloc = nTop - n0;
    int tid = threadIdx.x;
    if (tid < NB_NODES) hcnt[tid] = 0;
    int lo = bbase[b], hi = bbase[b + 1];
    int sz = hi - lo;
    bool fit = (sz <= PCAP);
    if (fit) {
        for (int i = tid; i < sz; i += 512) pe[i] = stg8[lo + i];
    }
    __syncthreads();
    if (fit) {
        for (int i = tid; i < sz; i += 512)
            atomicAdd(&hcnt[pe[i].x >> 17], 1);
    } else {
        for (int e = lo + tid; e < hi; e += 512)
            atomicAdd(&hcnt[stg8[e].x >> 17], 1);
    }
    __syncthreads();
    if (tid < NB_NODES) hinc[tid] = hcnt[tid];
    __syncthreads();
    for (int off = 1; off < NB_NODES; off <<= 1) {
        int v = (tid < NB_NODES && tid >= off) ? hinc[tid - off] : 0;
        __syncthreads();
        if (tid < NB_NODES) hinc[tid] += v;
        __syncthreads();
    }
    if (tid < nloc) {
        int excl = hinc[tid] - hcnt[tid];
        rowptr[n0 + tid] = lo + excl;
        hcnt[tid] = excl;               // reuse as cursor
    }
    if (b == K - 1 && tid == 0) rowptr[N] = hi;
    __syncthreads();
    if (fit) {
        for (int i = tid; i < sz; i += 512) {
            int2 p = pe[i];
            int pos = lo + atomicAdd(&hcnt[p.x >> 17], 1);
            perm[pos] = make_int2(p.x & 0x1FFFF, p.y);
        }
    } else {
        for (int e = lo + tid; e < hi; e += 512) {
            int2 p = stg8[e];
            int pos = lo + atomicAdd(&hcnt[p.x >> 17], 1);
            perm[pos] = make_int2(p.x & 0x1FFFF, p.y);
        }
    }
}

// ---------- gather aggregation over one L2-resident half-table ----------
// Half-table = [N][16] fp16 (32 B rows, 3.2 MB). One wave per node:
// 8 edge-slots x 8 lanes x 4 B (2 halves); unroll 2 -> 16 loads in flight.
// perm/out accessed nontemporally to keep the table resident in L2.
__global__ __launch_bounds__(256) void csr_agg_half(
    const int* __restrict__ rowptr, const int2* __restrict__ perm,
    const __half* __restrict__ tab, float* __restrict__ out, int N, int half)
{
    int gid = blockIdx.x * 256 + threadIdx.x;
    int n = gid >> 6;
    if (n >= N) return;
    int lane = threadIdx.x & 63;
    int slot = lane >> 3;     // 0..7 edge slot
    int q = lane & 7;         // 2-half group within 16-half row
    int e0 = rowptr[n], e1 = rowptr[n + 1];
    const unsigned* T = (const unsigned*)tab;   // row stride = 8 uints
    float ax0 = 0.f, ay0 = 0.f, ax1 = 0.f, ay1 = 0.f;
    const long long* P = (const long long*)perm;
    int e = e0 + slot;
    for (; e + 8 < e1; e += 16) {
        long long pv0 = __builtin_nontemporal_load(&P[e]);
        long long pv1 = __builtin_nontemporal_load(&P[e + 8]);
        int s0 = (int)(unsigned)pv0, s1 = (int)(unsigned)pv1;
        float w0 = __int_as_float((int)(pv0 >> 32));
        float w1 = __int_as_float((int)(pv1 >> 32));
        unsigned r0 = T[(size_t)s0 * 8 + q];
        unsigned r1 = T[(size_t)s1 * 8 + q];
        float2 f0 = __half22float2(*(__half2*)&r0);
        float2 f1 = __half22float2(*(__half2*)&r1);
        ax0 = fmaf(f0.x, w0, ax0); ay0 = fmaf(f0.y, w0, ay0);
        ax1 = fmaf(f1.x, w1, ax1); ay1 = fmaf(f1.y, w1, ay1);
    }
    for (; e < e1; e += 8) {
        long long pv = __builtin_nontemporal_load(&P[e]);
        int s = (int)(unsigned)pv;
        float w = __int_as_float((int)(pv >> 32));
        unsigned r = T[(size_t)s * 8 + q];
        float2 f = __half22float2(*(__half2*)&r);
        ax0 = fmaf(f.x, w, ax0); ay0 = fmaf(f.y, w, ay0);
    }
    ax0 += ax1; ay0 += ay1;
    #pragma unroll
    for (int off = 8; off < 64; off <<= 1) {
        ax0 += __shfl_xor(ax0, off, 64);
        ay0 += __shfl_xor(ay0, off, 64);
    }
    if (lane < 8) {
        float* O = out + (size_t)n * HID + half * 16 + q * 2;
        float o0 = __builtin_nontemporal_load(&O[0]);
        float o1 = __builtin_nontemporal_load(&O[1]);
        __builtin_nontemporal_store(o0 + ax0, &O[0]);
        __builtin_nontemporal_store(o1 + ay0, &O[1]);
    }
}

// ---------- fused pool + MLP: one block per graph, batch sorted ----------
__global__ __launch_bounds__(256) void pool_mlp(
    const float* __restrict__ C, const int* __restrict__ batch, int N,
    const float* __restrict__ W1, const float* __restrict__ b1,
    const float* __restrict__ W2, const float* __restrict__ b2,
    const float* __restrict__ W3, const float* __restrict__ b3,
    float* __restrict__ out)
{
    int g = blockIdx.x;
    int tid = threadIdx.x;
    int lo, hi;
    {
        int l = 0, r = N;
        while (l < r) { int m = (l + r) >> 1; if (batch[m] < g) l = m + 1; else r = m; }
        lo = l;
        r = N;
        while (l < r) { int m = (l + r) >> 1; if (batch[m] < g + 1) l = m + 1; else r = m; }
        hi = l;
    }
    __shared__ float ssum[8][32];
    __shared__ float gvec[32];
    __shared__ float h1v[32];
    __shared__ float h2v[16];
    int f = tid & 31, seg = tid >> 5;
    float acc = 0.f;
    for (int n = lo + seg; n < hi; n += 8) {
        float v = C[(size_t)n * HID + f];
        acc += v > 0.f ? v : 0.f;
    }
    ssum[seg][f] = acc;
    __syncthreads();
    if (tid < 32) {
        float s = 0.f;
        #pragma unroll
        for (int k = 0; k < 8; ++k) s += ssum[k][tid];
        float c = (float)(hi - lo); c = c > 1.f ? c : 1.f;
        gvec[tid] = s / c;
    }
    __syncthreads();
    if (tid < 32) {
        float a = b1[tid];
        #pragma unroll
        for (int k = 0; k < 32; ++k) a = fmaf(gvec[k], W1[k * 32 + tid], a);
        h1v[tid] = a > 0.f ? a : 0.f;
    }
    __syncthreads();
    if (tid < 16) {
        float a = b2[tid];
        #pragma unroll
        for (int k = 0; k < 32; ++k) a = fmaf(h1v[k], W2[k * 16 + tid], a);
        h2v[tid] = a > 0.f ? a : 0.f;
    }
    __syncthreads();
    if (tid == 0) {
        float o = b3[0];
        #pragma unroll
        for (int k = 0; k < 16; ++k) o = fmaf(h2v[k], W3[k], o);
        out[g] = o;
    }
}

extern "C" void kernel_launch(void* const* d_in, const int* in_sizes, int n_in,
                              void* d_out, int out_size, void* d_ws, size_t ws_size,
                              hipStream_t stream) {
    const float* x     = (const float*)d_in[0];
    const int*   ei    = (const int*)d_in[1];
    const float* ew    = (const float*)d_in[2];
    const int*   batch = (const int*)d_in[3];
    const float* c1rw  = (const float*)d_in[4];
    const float* c1rb  = (const float*)d_in[5];
    const float* c1ow  = (const float*)d_in[6];
    const float* c2rw  = (const float*)d_in[7];
    const float* c2rb  = (const float*)d_in[8];
    const float* c2ow  = (const float*)d_in[9];
    const float* l1w   = (const float*)d_in[10];
    const float* l1b   = (const float*)d_in[11];
    const float* l2w   = (const float*)d_in[12];
    const float* l2b   = (const float*)d_in[13];
    const float* lw    = (const float*)d_in[14];
    const float* lb    = (const float*)d_in[15];

    int N = in_sizes[0] / FIN;      // 100000
    int E = in_sizes[2];            // 1600000
    const int* src = ei;
    const int* dst = ei + E;
    int K    = (N + NB_NODES - 1) >> NB_SHIFT;   // 391 buckets (256 nodes)
    int NBLK = (E + EPB - 1) / EPB;              // 782 edge blocks

    // ---- workspace layout (with aliasing) ----
    char* ws = (char*)d_ws;
    size_t off = 0;
    auto alloc = [&](size_t nbytes) { void* p = ws + off; off += (nbytes + 255) & ~size_t(255); return p; };
    __half* A     = (__half*)alloc((size_t)N * HID * 2);   // two [N][16] half-tables
    float*  BC    = (float*) alloc((size_t)N * HID * 4);   // 12.8 MB
    int2*   perm  = (int2*)  alloc((size_t)E * 8);         // 12.8 MB
    int*   rowptr = (int*)   alloc((size_t)(N + 1) * 4);
    int*   btot   = (int*)   alloc((size_t)KMAX2 * 4);
    int*   bbase  = (int*)   alloc((size_t)(KMAX2 + 1) * 4);
    // aliases (dead before the producing kernels write A/BC):
    int*   cbb    = (int*)A;       // K*NBLK*4 = 1.22 MB < 6.4 MB, read last by partB
    int2*  stg8   = (int2*)BC;     // E*8 = 12.8 MB, read last by partC2

    __half* A0 = A;                    // features [0,16)
    __half* A1 = A + (size_t)N * 16;   // features [16,32)

    int nb_node = (N + NT - 1) / NT;
    int nb_agg  = (int)(((long long)N * 64 + 255) / 256);

    // partition build (no global atomics anywhere)
    bucket_hist<<<NBLK, 256, 0, stream>>>(dst, cbb, E, K, NBLK);
    bucket_scan<<<K, 256, 0, stream>>>(cbb, btot, NBLK);
    btot_scan<<<1, 256, 0, stream>>>(btot, bbase, K);
    partB<<<NBLK, 256, 0, stream>>>(src, dst, ew, cbb, bbase, stg8, E, K, NBLK);
    partC2<<<K, 512, 0, stream>>>(stg8, bbase, rowptr, perm, N, K);

    // conv1
    node_lin64<<<nb_node, 256, 0, stream>>>(x, c1rw, c1ow, c1rb, A, BC, N);
    csr_agg_half<<<nb_agg, 256, 0, stream>>>(rowptr, perm, A0, BC, N, 0);
    csr_agg_half<<<nb_agg, 256, 0, stream>>>(rowptr, perm, A1, BC, N, 1);
    // conv2 (relu fused into node_lin32 load; A overwritten with layer-2 rel-proj)
    node_lin32<<<nb_node, 256, 0, stream>>>(BC, c2rw, c2ow, c2rb, A, BC, N);
    csr_agg_half<<<nb_agg, 256, 0, stream>>>(rowptr, perm, A0, BC, N, 0);
    csr_agg_half<<<nb_agg, 256, 0, stream>>>(rowptr, perm, A1, BC, N, 1);
    // fused pool + MLP
    pool_mlp<<<NGRAPH, 256, 0, stream>>>(BC, batch, N, l1w, l1b, l2w, l2b, lw, lb,
                                         (float*)d_out);
}

// Round 16
// 175.903 us; speedup vs baseline: 1.5587x; 1.5587x over previous
//
#include <hip/hip_runtime.h>
#include <hip/hip_fp16.h>

#define NGRAPH 256
#define FIN 64
#define HID 32
#define NB_SHIFT 8            // 256 nodes per bucket
#define NB_NODES 256
#define KMAX2 512
#define EPB 2048              // edges per partition block
#define EPT 8                 // edges per thread (256 threads)
#define NT 64                 // nodes per GEMM block
#define XPAD 65               // 64 + 1 pad (floats) per staged x row
#define HPAD 33               // 32 + 1 pad
#define PCAP 6016             // partC2 LDS edge-staging capacity

// ---------- fused: bucket_hist (blocks [0,NBLK)) + node_lin64 (rest) ----------
// hist and the conv1 linear are mutually independent; co-scheduling hides the
// ~10us hist under the ~20us GEMM.  LDS is a union (33 KB -> 4 blocks/CU).
union SU {
    int h[KMAX2];
    struct { float Wr[FIN * HID]; float Wo[FIN * HID]; float b[HID];
             float x[NT * XPAD]; } g;
};

__global__ __launch_bounds__(256, 4) void hist_lin64(
    const int* __restrict__ dst, int* __restrict__ cbb, int E, int K, int NBLK,
    const float* __restrict__ x, const float* __restrict__ Wrel,
    const float* __restrict__ Wroot, const float* __restrict__ bias,
    __half* __restrict__ A, float* __restrict__ B, int N)
{
    __shared__ SU u;
    int tid = threadIdx.x;
    if (blockIdx.x < (unsigned)NBLK) {
        // ---- histogram role ----
        for (int i = tid; i < K; i += 256) u.h[i] = 0;
        __syncthreads();
        int e0 = blockIdx.x * EPB + tid * 8;
        if (e0 + 7 < E) {
            int4 d0 = *reinterpret_cast<const int4*>(dst + e0);
            int4 d1 = *reinterpret_cast<const int4*>(dst + e0 + 4);
            atomicAdd(&u.h[d0.x >> NB_SHIFT], 1); atomicAdd(&u.h[d0.y >> NB_SHIFT], 1);
            atomicAdd(&u.h[d0.z >> NB_SHIFT], 1); atomicAdd(&u.h[d0.w >> NB_SHIFT], 1);
            atomicAdd(&u.h[d1.x >> NB_SHIFT], 1); atomicAdd(&u.h[d1.y >> NB_SHIFT], 1);
            atomicAdd(&u.h[d1.z >> NB_SHIFT], 1); atomicAdd(&u.h[d1.w >> NB_SHIFT], 1);
        } else {
            for (int e = e0; e < E && e < e0 + 8; ++e)
                atomicAdd(&u.h[dst[e] >> NB_SHIFT], 1);
        }
        __syncthreads();
        for (int i = tid; i < K; i += 256)
            cbb[(size_t)i * NBLK + blockIdx.x] = u.h[i];
        return;
    }
    // ---- conv1 linear role ----
    {
        const float4* Wr4 = (const float4*)Wrel;
        const float4* Wo4 = (const float4*)Wroot;
        for (int i = tid; i < FIN * HID / 4; i += 256) {
            ((float4*)u.g.Wr)[i] = Wr4[i];
            ((float4*)u.g.Wo)[i] = Wo4[i];
        }
        if (tid < HID) u.g.b[tid] = bias[tid];
    }
    int base = (blockIdx.x - NBLK) * NT;
    {
        const float4* x4 = (const float4*)x;
        for (int i = tid; i < NT * 16; i += 256) {
            int row = i >> 4, c4 = i & 15;
            int n = base + row;
            float4 v = (n < N) ? x4[(size_t)n * 16 + c4]
                               : make_float4(0.f, 0.f, 0.f, 0.f);
            *(float4*)&u.g.x[row * XPAD + c4 * 4] = v;
        }
    }
    __syncthreads();

    int nl = tid >> 3;          // 0..31
    int fq = (tid & 7) * 4;     // feature quad base
    const float* xa = &u.g.x[nl * XPAD];
    const float* xb = &u.g.x[(nl + 32) * XPAD];
    float4 ar0 = make_float4(0.f,0.f,0.f,0.f), ao0 = ar0;
    float4 ar1 = ar0, ao1 = ar0;
    #pragma unroll 4
    for (int k = 0; k < FIN; ++k) {
        float4 w4 = *(const float4*)&u.g.Wr[k * HID + fq];
        float4 o4 = *(const float4*)&u.g.Wo[k * HID + fq];
        float va = xa[k], vb = xb[k];
        ar0.x = fmaf(va, w4.x, ar0.x); ar0.y = fmaf(va, w4.y, ar0.y);
        ar0.z = fmaf(va, w4.z, ar0.z); ar0.w = fmaf(va, w4.w, ar0.w);
        ao0.x = fmaf(va, o4.x, ao0.x); ao0.y = fmaf(va, o4.y, ao0.y);
        ao0.z = fmaf(va, o4.z, ao0.z); ao0.w = fmaf(va, o4.w, ao0.w);
        ar1.x = fmaf(vb, w4.x, ar1.x); ar1.y = fmaf(vb, w4.y, ar1.y);
        ar1.z = fmaf(vb, w4.z, ar1.z); ar1.w = fmaf(vb, w4.w, ar1.w);
        ao1.x = fmaf(vb, o4.x, ao1.x); ao1.y = fmaf(vb, o4.y, ao1.y);
        ao1.z = fmaf(vb, o4.z, ao1.z); ao1.w = fmaf(vb, o4.w, ao1.w);
    }
    float4 bb = *(const float4*)&u.g.b[fq];
    int n0 = base + nl, n1 = base + nl + 32;
    if (n0 < N) {
        __half2 pa = __floats2half2_rn(ar0.x, ar0.y);
        __half2 pb = __floats2half2_rn(ar0.z, ar0.w);
        uint2 pk; pk.x = *(unsigned*)&pa; pk.y = *(unsigned*)&pb;
        *(uint2*)&A[(size_t)n0 * HID + fq] = pk;
        ao0.x += bb.x; ao0.y += bb.y; ao0.z += bb.z; ao0.w += bb.w;
        *(float4*)&B[(size_t)n0 * HID + fq] = ao0;
    }
    if (n1 < N) {
        __half2 pa = __floats2half2_rn(ar1.x, ar1.y);
        __half2 pb = __floats2half2_rn(ar1.z, ar1.w);
        uint2 pk; pk.x = *(unsigned*)&pa; pk.y = *(unsigned*)&pb;
        *(uint2*)&A[(size_t)n1 * HID + fq] = pk;
        ao1.x += bb.x; ao1.y += bb.y; ao1.z += bb.z; ao1.w += bb.w;
        *(float4*)&B[(size_t)n1 * HID + fq] = ao1;
    }
}

// ---------- node GEMM 2: relu fused on load, FIN=32 ----------
__global__ __launch_bounds__(256, 4) void node_lin32(
    const float* __restrict__ Hpre, const float* __restrict__ Wrel,
    const float* __restrict__ Wroot, const float* __restrict__ bias,
    __half* __restrict__ A, float* __restrict__ C, int N)
{
    __shared__ float sWr[HID * HID];      // 4 KB
    __shared__ float sWo[HID * HID];
    __shared__ float sb[HID];
    __shared__ float sh[NT * HPAD];       // 8.4 KB
    int tid = threadIdx.x;
    {
        const float4* Wr4 = (const float4*)Wrel;
        const float4* Wo4 = (const float4*)Wroot;
        for (int i = tid; i < HID * HID / 4; i += 256) {
            ((float4*)sWr)[i] = Wr4[i];
            ((float4*)sWo)[i] = Wo4[i];
        }
        if (tid < HID) sb[tid] = bias[tid];
    }
    int base = blockIdx.x * NT;
    {
        const float4* H4 = (const float4*)Hpre;
        for (int i = tid; i < NT * 8; i += 256) {
            int row = i >> 3, c4 = i & 7;
            int n = base + row;
            float4 v = make_float4(0.f, 0.f, 0.f, 0.f);
            if (n < N) {
                v = H4[(size_t)n * 8 + c4];
                v.x = v.x > 0.f ? v.x : 0.f; v.y = v.y > 0.f ? v.y : 0.f;
                v.z = v.z > 0.f ? v.z : 0.f; v.w = v.w > 0.f ? v.w : 0.f;
            }
            *(float4*)&sh[row * HPAD + c4 * 4] = v;
        }
    }
    __syncthreads();

    int nl = tid >> 3;
    int fq = (tid & 7) * 4;
    const float* xa = &sh[nl * HPAD];
    const float* xb = &sh[(nl + 32) * HPAD];
    float4 ar0 = make_float4(0.f,0.f,0.f,0.f), ao0 = ar0;
    float4 ar1 = ar0, ao1 = ar0;
    #pragma unroll 4
    for (int k = 0; k < HID; ++k) {
        float4 w4 = *(const float4*)&sWr[k * HID + fq];
        float4 o4 = *(const float4*)&sWo[k * HID + fq];
        float va = xa[k], vb = xb[k];
        ar0.x = fmaf(va, w4.x, ar0.x); ar0.y = fmaf(va, w4.y, ar0.y);
        ar0.z = fmaf(va, w4.z, ar0.z); ar0.w = fmaf(va, w4.w, ar0.w);
        ao0.x = fmaf(va, o4.x, ao0.x); ao0.y = fmaf(va, o4.y, ao0.y);
        ao0.z = fmaf(va, o4.z, ao0.z); ao0.w = fmaf(va, o4.w, ao0.w);
        ar1.x = fmaf(vb, w4.x, ar1.x); ar1.y = fmaf(vb, w4.y, ar1.y);
        ar1.z = fmaf(vb, w4.z, ar1.z); ar1.w = fmaf(vb, w4.w, ar1.w);
        ao1.x = fmaf(vb, o4.x, ao1.x); ao1.y = fmaf(vb, o4.y, ao1.y);
        ao1.z = fmaf(vb, o4.z, ao1.z); ao1.w = fmaf(vb, o4.w, ao1.w);
    }
    float4 bb = *(const float4*)&sb[fq];
    int n0 = base + nl, n1 = base + nl + 32;
    if (n0 < N) {
        __half2 pa = __floats2half2_rn(ar0.x, ar0.y);
        __half2 pb = __floats2half2_rn(ar0.z, ar0.w);
        uint2 pk; pk.x = *(unsigned*)&pa; pk.y = *(unsigned*)&pb;
        *(uint2*)&A[(size_t)n0 * HID + fq] = pk;
        ao0.x += bb.x; ao0.y += bb.y; ao0.z += bb.z; ao0.w += bb.w;
        *(float4*)&C[(size_t)n0 * HID + fq] = ao0;
    }
    if (n1 < N) {
        __half2 pa = __floats2half2_rn(ar1.x, ar1.y);
        __half2 pb = __floats2half2_rn(ar1.z, ar1.w);
        uint2 pk; pk.x = *(unsigned*)&pa; pk.y = *(unsigned*)&pb;
        *(uint2*)&A[(size_t)n1 * HID + fq] = pk;
        ao1.x += bb.x; ao1.y += bb.y; ao1.z += bb.z; ao1.w += bb.w;
        *(float4*)&C[(size_t)n1 * HID + fq] = ao1;
    }
}

// ---------- rest of the deterministic partition build ----------

__global__ __launch_bounds__(256) void bucket_scan(
    int* __restrict__ cbb, int* __restrict__ btot, int NBLK)
{
    __shared__ int sc[256];
    size_t row = (size_t)blockIdx.x * NBLK;
    int t = threadIdx.x;
    int base = t * 4;
    int v[4]; int s = 0;
    #pragma unroll
    for (int j = 0; j < 4; ++j) { v[j] = (base + j < NBLK) ? cbb[row + base + j] : 0; s += v[j]; }
    sc[t] = s;
    __syncthreads();
    int acc = s;
    for (int off = 1; off < 256; off <<= 1) {
        int add = (t >= off) ? sc[t - off] : 0;
        __syncthreads();
        acc += add;
        sc[t] = acc;
        __syncthreads();
    }
    int run = acc - s;
    #pragma unroll
    for (int j = 0; j < 4; ++j) {
        if (base + j < NBLK) cbb[row + base + j] = run;
        run += v[j];
    }
    if (t == 255) btot[blockIdx.x] = acc;
}

__global__ __launch_bounds__(256) void btot_scan(
    const int* __restrict__ btot, int* __restrict__ bbase, int K)
{
    __shared__ int sc[256];
    int t = threadIdx.x;
    int base = t * 4;
    int v[4]; int s = 0;
    #pragma unroll
    for (int j = 0; j < 4; ++j) { v[j] = (base + j < K) ? btot[base + j] : 0; s += v[j]; }
    sc[t] = s;
    __syncthreads();
    int acc = s;
    for (int off = 1; off < 256; off <<= 1) {
        int add = (t >= off) ? sc[t - off] : 0;
        __syncthreads();
        acc += add;
        sc[t] = acc;
        __syncthreads();
    }
    int run = acc - s;
    #pragma unroll
    for (int j = 0; j < 4; ++j) {
        if (base + j < K) bbase[base + j] = run;
        run += v[j];
    }
    if (t == 255) bbase[K] = acc;
}

// partition: edges -> bucket-grouped staging; payload = {src | dloc<<17, ew}
__global__ __launch_bounds__(256) void partB(
    const int* __restrict__ src, const int* __restrict__ dst,
    const float* __restrict__ ew, const int* __restrict__ cbb,
    const int* __restrict__ bbase, int2* __restrict__ stg8,
    int E, int K, int NBLK)
{
    __shared__ int4 pay[EPB];       // 32 KB: {meta, ew, tgt, pad}
    __shared__ int h[KMAX2];
    __shared__ int lofs[KMAX2];
    __shared__ int gb[KMAX2];
    __shared__ int sc[256];
    int tid = threadIdx.x;
    for (int i = tid; i < K; i += 256) h[i] = 0;
    __syncthreads();

    int base = blockIdx.x * EPB;
    int es[EPT], ds[EPT]; float wsr[EPT];
    #pragma unroll
    for (int k = 0; k < EPT; ++k) {
        int e = base + k * 256 + tid;
        if (e < E) {
            es[k] = src[e]; ds[k] = dst[e]; wsr[k] = ew[e];
            atomicAdd(&h[ds[k] >> NB_SHIFT], 1);
        } else ds[k] = -1;
    }
    __syncthreads();

    int b0 = tid * 2;
    int v0 = (b0 < K) ? h[b0] : 0;
    int v1 = (b0 + 1 < K) ? h[b0 + 1] : 0;
    int s = v0 + v1;
    sc[tid] = s;
    __syncthreads();
    int acc = s;
    for (int off = 1; off < 256; off <<= 1) {
        int add = (tid >= off) ? sc[tid - off] : 0;
        __syncthreads();
        acc += add;
        sc[tid] = acc;
        __syncthreads();
    }
    int run = acc - s;
    if (b0 < K) lofs[b0] = run;
    if (b0 + 1 < K) lofs[b0 + 1] = run + v0;
    __syncthreads();

    for (int b = tid; b < K; b += 256) {
        gb[b] = bbase[b] + cbb[(size_t)b * NBLK + blockIdx.x];
        h[b] = lofs[b];
    }
    __syncthreads();

    #pragma unroll
    for (int k = 0; k < EPT; ++k) {
        if (ds[k] >= 0) {
            int b = ds[k] >> NB_SHIFT;
            int dloc = ds[k] & (NB_NODES - 1);
            int slot = atomicAdd(&h[b], 1);
            pay[slot] = make_int4(es[k] | (dloc << 17), __float_as_int(wsr[k]),
                                  gb[b] + slot - lofs[b], 0);
        }
    }
    __syncthreads();

    int tot = E - base; if (tot > EPB) tot = EPB;
    for (int i = tid; i < tot; i += 256) {
        int4 p = pay[i];
        stg8[p.z] = make_int2(p.x, p.y);
    }
}

// per bucket: counting-sort edges by dst node, LDS-staged single-pass
__global__ __launch_bounds__(512) void partC2(
    const int2* __restrict__ stg8, const int* __restrict__ bbase,
    int* __restrict__ rowptr, int2* __restrict__ perm, int N, int K)
{
    __shared__ int2 pe[PCAP];          // 47 KB edge staging
    __shared__ int hcnt[NB_NODES];
    __shared__ int hinc[NB_NODES];
    int b = blockIdx.x;
    int n0 = b << NB_SHIFT;
    int nTop = n0 + NB_NODES; if (nTop > N) nTop = N;
    int nloc = nTop - n0;
    int tid = threadIdx.x;
    if (tid < NB_NODES) hcnt[tid] = 0;
    int lo = bbase[b], hi = bbase[b + 1];
    int sz = hi - lo;
    bool fit = (sz <= PCAP);
    if (fit) {
        for (int i = tid; i < sz; i += 512) pe[i] = stg8[lo + i];
    }
    __syncthreads();
    if (fit) {
        for (int i = tid; i < sz; i += 512)
            atomicAdd(&hcnt[pe[i].x >> 17], 1);
    } else {
        for (int e = lo + tid; e < hi; e += 512)
            atomicAdd(&hcnt[stg8[e].x >> 17], 1);
    }
    __syncthreads();
    if (tid < NB_NODES) hinc[tid] = hcnt[tid];
    __syncthreads();
    for (int off = 1; off < NB_NODES; off <<= 1) {
        int v = (tid < NB_NODES && tid >= off) ? hinc[tid - off] : 0;
        __syncthreads();
        if (tid < NB_NODES) hinc[tid] += v;
        __syncthreads();
    }
    if (tid < nloc) {
        int excl = hinc[tid] - hcnt[tid];
        rowptr[n0 + tid] = lo + excl;
        hcnt[tid] = excl;               // reuse as cursor
    }
    if (b == K - 1 && tid == 0) rowptr[N] = hi;
    __syncthreads();
    if (fit) {
        for (int i = tid; i < sz; i += 512) {
            int2 p = pe[i];
            int pos = lo + atomicAdd(&hcnt[p.x >> 17], 1);
            perm[pos] = make_int2(p.x & 0x1FFFF, p.y);
        }
    } else {
        for (int e = lo + tid; e < hi; e += 512) {
            int2 p = stg8[e];
            int pos = lo + atomicAdd(&hcnt[p.x >> 17], 1);
            perm[pos] = make_int2(p.x & 0x1FFFF, p.y);
        }
    }
}

// ---------- gather-side aggregation (A in fp16: 64 B per row) ----------
// one wave per node: 8 edge-slots x 8 lanes x uint2(4 halves); unroll 2
__global__ __launch_bounds__(256) void csr_agg(
    const int* __restrict__ rowptr, const int2* __restrict__ perm,
    const __half* __restrict__ A, float* __restrict__ out, int N)
{
    int gid = blockIdx.x * 256 + threadIdx.x;
    int n = gid >> 6;
    if (n >= N) return;
    int lane = threadIdx.x & 63;
    int slot = lane >> 3;     // 0..7 edge slot
    int q = lane & 7;         // 4-half group within 32-half row
    int e0 = rowptr[n], e1 = rowptr[n + 1];
    const uint2* A2 = (const uint2*)A;   // row stride = 8 uint2
    float4 a0 = make_float4(0.f, 0.f, 0.f, 0.f);
    float4 a1 = make_float4(0.f, 0.f, 0.f, 0.f);
    int e = e0 + slot;
    for (; e + 8 < e1; e += 16) {
        int2 p0 = perm[e];
        int2 p1 = perm[e + 8];
        uint2 r0 = A2[(size_t)p0.x * 8 + q];
        uint2 r1 = A2[(size_t)p1.x * 8 + q];
        float w0 = __int_as_float(p0.y), w1 = __int_as_float(p1.y);
        float2 f01 = __half22float2(*(__half2*)&r0.x);
        float2 f23 = __half22float2(*(__half2*)&r0.y);
        float2 g01 = __half22float2(*(__half2*)&r1.x);
        float2 g23 = __half22float2(*(__half2*)&r1.y);
        a0.x = fmaf(f01.x, w0, a0.x); a0.y = fmaf(f01.y, w0, a0.y);
        a0.z = fmaf(f23.x, w0, a0.z); a0.w = fmaf(f23.y, w0, a0.w);
        a1.x = fmaf(g01.x, w1, a1.x); a1.y = fmaf(g01.y, w1, a1.y);
        a1.z = fmaf(g23.x, w1, a1.z); a1.w = fmaf(g23.y, w1, a1.w);
    }
    for (; e < e1; e += 8) {
        int2 p = perm[e];
        uint2 r = A2[(size_t)p.x * 8 + q];
        float w = __int_as_float(p.y);
        float2 f01 = __half22float2(*(__half2*)&r.x);
        float2 f23 = __half22float2(*(__half2*)&r.y);
        a0.x = fmaf(f01.x, w, a0.x); a0.y = fmaf(f01.y, w, a0.y);
        a0.z = fmaf(f23.x, w, a0.z); a0.w = fmaf(f23.y, w, a0.w);
    }
    a0.x += a1.x; a0.y += a1.y; a0.z += a1.z; a0.w += a1.w;
    #pragma unroll
    for (int off = 8; off < 64; off <<= 1) {
        a0.x += __shfl_xor(a0.x, off, 64);
        a0.y += __shfl_xor(a0.y, off, 64);
        a0.z += __shfl_xor(a0.z, off, 64);
        a0.w += __shfl_xor(a0.w, off, 64);
    }
    if (lane < 8) {
        float4* O4 = (float4*)out;
        size_t oi = (size_t)n * 8 + q;
        float4 o = O4[oi];
        o.x += a0.x; o.y += a0.y; o.z += a0.z; o.w += a0.w;
        O4[oi] = o;
    }
}

// ---------- fused pool + MLP: one block per graph, batch sorted ----------
__global__ __launch_bounds__(256) void pool_mlp(
    const float* __restrict__ C, const int* __restrict__ batch, int N,
    const float* __restrict__ W1, const float* __restrict__ b1,
    const float* __restrict__ W2, const float* __restrict__ b2,
    const float* __restrict__ W3, const float* __restrict__ b3,
    float* __restrict__ out)
{
    int g = blockIdx.x;
    int tid = threadIdx.x;
    int lo, hi;
    {
        int l = 0, r = N;
        while (l < r) { int m = (l + r) >> 1; if (batch[m] < g) l = m + 1; else r = m; }
        lo = l;
        r = N;
        while (l < r) { int m = (l + r) >> 1; if (batch[m] < g + 1) l = m + 1; else r = m; }
        hi = l;
    }
    __shared__ float ssum[8][32];
    __shared__ float gvec[32];
    __shared__ float h1v[32];
    __shared__ float h2v[16];
    int f = tid & 31, seg = tid >> 5;
    float acc = 0.f;
    for (int n = lo + seg; n < hi; n += 8) {
        float v = C[(size_t)n * HID + f];
        acc += v > 0.f ? v : 0.f;
    }
    ssum[seg][f] = acc;
    __syncthreads();
    if (tid < 32) {
        float s = 0.f;
        #pragma unroll
        for (int k = 0; k < 8; ++k) s += ssum[k][tid];
        float c = (float)(hi - lo); c = c > 1.f ? c : 1.f;
        gvec[tid] = s / c;
    }
    __syncthreads();
    if (tid < 32) {
        float a = b1[tid];
        #pragma unroll
        for (int k = 0; k < 32; ++k) a = fmaf(gvec[k], W1[k * 32 + tid], a);
        h1v[tid] = a > 0.f ? a : 0.f;
    }
    __syncthreads();
    if (tid < 16) {
        float a = b2[tid];
        #pragma unroll
        for (int k = 0; k < 32; ++k) a = fmaf(h1v[k], W2[k * 16 + tid], a);
        h2v[tid] = a > 0.f ? a : 0.f;
    }
    __syncthreads();
    if (tid == 0) {
        float o = b3[0];
        #pragma unroll
        for (int k = 0; k < 16; ++k) o = fmaf(h2v[k], W3[k], o);
        out[g] = o;
    }
}

extern "C" void kernel_launch(void* const* d_in, const int* in_sizes, int n_in,
                              void* d_out, int out_size, void* d_ws, size_t ws_size,
                              hipStream_t stream) {
    const float* x     = (const float*)d_in[0];
    const int*   ei    = (const int*)d_in[1];
    const float* ew    = (const float*)d_in[2];
    const int*   batch = (const int*)d_in[3];
    const float* c1rw  = (const float*)d_in[4];
    const float* c1rb  = (const float*)d_in[5];
    const float* c1ow  = (const float*)d_in[6];
    const float* c2rw  = (const float*)d_in[7];
    const float* c2rb  = (const float*)d_in[8];
    const float* c2ow  = (const float*)d_in[9];
    const float* l1w   = (const float*)d_in[10];
    const float* l1b   = (const float*)d_in[11];
    const float* l2w   = (const float*)d_in[12];
    const float* l2b   = (const float*)d_in[13];
    const float* lw    = (const float*)d_in[14];
    const float* lb    = (const float*)d_in[15];

    int N = in_sizes[0] / FIN;      // 100000
    int E = in_sizes[2];            // 1600000
    const int* src = ei;
    const int* dst = ei + E;
    int K    = (N + NB_NODES - 1) >> NB_SHIFT;   // 391 buckets (256 nodes)
    int NBLK = (E + EPB - 1) / EPB;              // 782 edge blocks

    // ---- workspace layout (NO aliasing: lin64 runs concurrently with build) ----
    char* ws = (char*)d_ws;
    size_t off = 0;
    auto alloc = [&](size_t nbytes) { void* p = ws + off; off += (nbytes + 255) & ~size_t(255); return p; };
    __half* A     = (__half*)alloc((size_t)N * HID * 2);        // 6.4 MB (fp16)
    float*  BC    = (float*) alloc((size_t)N * HID * 4);        // 12.8 MB
    int2*   perm  = (int2*)  alloc((size_t)E * 8);              // 12.8 MB
    int2*   stg8  = (int2*)  alloc((size_t)E * 8);              // 12.8 MB
    int*    cbb   = (int*)   alloc((size_t)K * NBLK * 4);       // 1.22 MB
    int*   rowptr = (int*)   alloc((size_t)(N + 1) * 4);
    int*   btot   = (int*)   alloc((size_t)KMAX2 * 4);
    int*   bbase  = (int*)   alloc((size_t)(KMAX2 + 1) * 4);

    int nb_node = (N + NT - 1) / NT;
    int nb_agg  = (int)(((long long)N * 64 + 255) / 256);

    // fused: histogram (NBLK blocks) || conv1 linear (nb_node blocks)
    hist_lin64<<<NBLK + nb_node, 256, 0, stream>>>(
        dst, cbb, E, K, NBLK, x, c1rw, c1ow, c1rb, A, BC, N);
    // rest of partition build
    bucket_scan<<<K, 256, 0, stream>>>(cbb, btot, NBLK);
    btot_scan<<<1, 256, 0, stream>>>(btot, bbase, K);
    partB<<<NBLK, 256, 0, stream>>>(src, dst, ew, cbb, bbase, stg8, E, K, NBLK);
    partC2<<<K, 512, 0, stream>>>(stg8, bbase, rowptr, perm, N, K);

    // conv1 aggregation
    csr_agg<<<nb_agg, 256, 0, stream>>>(rowptr, perm, A, BC, N);
    // conv2 (relu fused into node_lin32 load; A overwritten with layer-2 rel-proj)
    node_lin32<<<nb_node, 256, 0, stream>>>(BC, c2rw, c2ow, c2rb, A, BC, N);
    csr_agg<<<nb_agg, 256, 0, stream>>>(rowptr, perm, A, BC, N);
    // fused pool + MLP
    pool_mlp<<<NGRAPH, 256, 0, stream>>>(BC, batch, N, l1w, l1b, l2w, l2b, lw, lb,
                                         (float*)d_out);
}

// Round 17
// 160.918 us; speedup vs baseline: 1.7038x; 1.0931x over previous
//
#include <hip/hip_runtime.h>
#include <hip/hip_fp16.h>

#define NGRAPH 256
#define FIN 64
#define HID 32
#define NB_SHIFT 8            // 256 nodes per bucket
#define NB_NODES 256
#define KMAX2 512
#define EPB 2048              // edges per partition block
#define EPT 8                 // edges per thread (256 threads)
#define NT 64                 // nodes per GEMM block
#define XPAD 65               // 64 + 1 pad (floats) per staged x row
#define HPAD 33               // 32 + 1 pad
#define PCAP 6016             // partC2 LDS edge-staging capacity

// ---------- fused: bucket_hist (blocks [0,NBLK)) + node_lin64 (rest) ----------
union SU {
    int h[KMAX2];
    struct { float Wr[FIN * HID]; float Wo[FIN * HID]; float b[HID];
             float x[NT * XPAD]; } g;
};

__global__ __launch_bounds__(256, 4) void hist_lin64(
    const int* __restrict__ dst, int* __restrict__ cbb, int E, int K, int NBLK,
    const float* __restrict__ x, const float* __restrict__ Wrel,
    const float* __restrict__ Wroot, const float* __restrict__ bias,
    __half* __restrict__ A, float* __restrict__ B, int N)
{
    __shared__ SU u;
    int tid = threadIdx.x;
    if (blockIdx.x < (unsigned)NBLK) {
        // ---- histogram role ----
        for (int i = tid; i < K; i += 256) u.h[i] = 0;
        __syncthreads();
        int e0 = blockIdx.x * EPB + tid * 8;
        if (e0 + 7 < E) {
            int4 d0 = *reinterpret_cast<const int4*>(dst + e0);
            int4 d1 = *reinterpret_cast<const int4*>(dst + e0 + 4);
            atomicAdd(&u.h[d0.x >> NB_SHIFT], 1); atomicAdd(&u.h[d0.y >> NB_SHIFT], 1);
            atomicAdd(&u.h[d0.z >> NB_SHIFT], 1); atomicAdd(&u.h[d0.w >> NB_SHIFT], 1);
            atomicAdd(&u.h[d1.x >> NB_SHIFT], 1); atomicAdd(&u.h[d1.y >> NB_SHIFT], 1);
            atomicAdd(&u.h[d1.z >> NB_SHIFT], 1); atomicAdd(&u.h[d1.w >> NB_SHIFT], 1);
        } else {
            for (int e = e0; e < E && e < e0 + 8; ++e)
                atomicAdd(&u.h[dst[e] >> NB_SHIFT], 1);
        }
        __syncthreads();
        for (int i = tid; i < K; i += 256)
            cbb[(size_t)i * NBLK + blockIdx.x] = u.h[i];
        return;
    }
    // ---- conv1 linear role ----
    {
        const float4* Wr4 = (const float4*)Wrel;
        const float4* Wo4 = (const float4*)Wroot;
        for (int i = tid; i < FIN * HID / 4; i += 256) {
            ((float4*)u.g.Wr)[i] = Wr4[i];
            ((float4*)u.g.Wo)[i] = Wo4[i];
        }
        if (tid < HID) u.g.b[tid] = bias[tid];
    }
    int base = (blockIdx.x - NBLK) * NT;
    {
        const float4* x4 = (const float4*)x;
        for (int i = tid; i < NT * 16; i += 256) {
            int row = i >> 4, c4 = i & 15;
            int n = base + row;
            float4 v = (n < N) ? x4[(size_t)n * 16 + c4]
                               : make_float4(0.f, 0.f, 0.f, 0.f);
            *(float4*)&u.g.x[row * XPAD + c4 * 4] = v;
        }
    }
    __syncthreads();

    int nl = tid >> 3;          // 0..31
    int fq = (tid & 7) * 4;     // feature quad base
    const float* xa = &u.g.x[nl * XPAD];
    const float* xb = &u.g.x[(nl + 32) * XPAD];
    float4 ar0 = make_float4(0.f,0.f,0.f,0.f), ao0 = ar0;
    float4 ar1 = ar0, ao1 = ar0;
    #pragma unroll 4
    for (int k = 0; k < FIN; ++k) {
        float4 w4 = *(const float4*)&u.g.Wr[k * HID + fq];
        float4 o4 = *(const float4*)&u.g.Wo[k * HID + fq];
        float va = xa[k], vb = xb[k];
        ar0.x = fmaf(va, w4.x, ar0.x); ar0.y = fmaf(va, w4.y, ar0.y);
        ar0.z = fmaf(va, w4.z, ar0.z); ar0.w = fmaf(va, w4.w, ar0.w);
        ao0.x = fmaf(va, o4.x, ao0.x); ao0.y = fmaf(va, o4.y, ao0.y);
        ao0.z = fmaf(va, o4.z, ao0.z); ao0.w = fmaf(va, o4.w, ao0.w);
        ar1.x = fmaf(vb, w4.x, ar1.x); ar1.y = fmaf(vb, w4.y, ar1.y);
        ar1.z = fmaf(vb, w4.z, ar1.z); ar1.w = fmaf(vb, w4.w, ar1.w);
        ao1.x = fmaf(vb, o4.x, ao1.x); ao1.y = fmaf(vb, o4.y, ao1.y);
        ao1.z = fmaf(vb, o4.z, ao1.z); ao1.w = fmaf(vb, o4.w, ao1.w);
    }
    float4 bb = *(const float4*)&u.g.b[fq];
    int n0 = base + nl, n1 = base + nl + 32;
    if (n0 < N) {
        __half2 pa = __floats2half2_rn(ar0.x, ar0.y);
        __half2 pb = __floats2half2_rn(ar0.z, ar0.w);
        uint2 pk; pk.x = *(unsigned*)&pa; pk.y = *(unsigned*)&pb;
        *(uint2*)&A[(size_t)n0 * HID + fq] = pk;
        ao0.x += bb.x; ao0.y += bb.y; ao0.z += bb.z; ao0.w += bb.w;
        *(float4*)&B[(size_t)n0 * HID + fq] = ao0;
    }
    if (n1 < N) {
        __half2 pa = __floats2half2_rn(ar1.x, ar1.y);
        __half2 pb = __floats2half2_rn(ar1.z, ar1.w);
        uint2 pk; pk.x = *(unsigned*)&pa; pk.y = *(unsigned*)&pb;
        *(uint2*)&A[(size_t)n1 * HID + fq] = pk;
        ao1.x += bb.x; ao1.y += bb.y; ao1.z += bb.z; ao1.w += bb.w;
        *(float4*)&B[(size_t)n1 * HID + fq] = ao1;
    }
}

// ---------- node GEMM 2: relu fused on load, FIN=32 ----------
__global__ __launch_bounds__(256, 4) void node_lin32(
    const float* __restrict__ Hpre, const float* __restrict__ Wrel,
    const float* __restrict__ Wroot, const float* __restrict__ bias,
    __half* __restrict__ A, float* __restrict__ C, int N)
{
    __shared__ float sWr[HID * HID];      // 4 KB
    __shared__ float sWo[HID * HID];
    __shared__ float sb[HID];
    __shared__ float sh[NT * HPAD];       // 8.4 KB
    int tid = threadIdx.x;
    {
        const float4* Wr4 = (const float4*)Wrel;
        const float4* Wo4 = (const float4*)Wroot;
        for (int i = tid; i < HID * HID / 4; i += 256) {
            ((float4*)sWr)[i] = Wr4[i];
            ((float4*)sWo)[i] = Wo4[i];
        }
        if (tid < HID) sb[tid] = bias[tid];
    }
    int base = blockIdx.x * NT;
    {
        const float4* H4 = (const float4*)Hpre;
        for (int i = tid; i < NT * 8; i += 256) {
            int row = i >> 3, c4 = i & 7;
            int n = base + row;
            float4 v = make_float4(0.f, 0.f, 0.f, 0.f);
            if (n < N) {
                v = H4[(size_t)n * 8 + c4];
                v.x = v.x > 0.f ? v.x : 0.f; v.y = v.y > 0.f ? v.y : 0.f;
                v.z = v.z > 0.f ? v.z : 0.f; v.w = v.w > 0.f ? v.w : 0.f;
            }
            *(float4*)&sh[row * HPAD + c4 * 4] = v;
        }
    }
    __syncthreads();

    int nl = tid >> 3;
    int fq = (tid & 7) * 4;
    const float* xa = &sh[nl * HPAD];
    const float* xb = &sh[(nl + 32) * HPAD];
    float4 ar0 = make_float4(0.f,0.f,0.f,0.f), ao0 = ar0;
    float4 ar1 = ar0, ao1 = ar0;
    #pragma unroll 4
    for (int k = 0; k < HID; ++k) {
        float4 w4 = *(const float4*)&sWr[k * HID + fq];
        float4 o4 = *(const float4*)&sWo[k * HID + fq];
        float va = xa[k], vb = xb[k];
        ar0.x = fmaf(va, w4.x, ar0.x); ar0.y = fmaf(va, w4.y, ar0.y);
        ar0.z = fmaf(va, w4.z, ar0.z); ar0.w = fmaf(va, w4.w, ar0.w);
        ao0.x = fmaf(va, o4.x, ao0.x); ao0.y = fmaf(va, o4.y, ao0.y);
        ao0.z = fmaf(va, o4.z, ao0.z); ao0.w = fmaf(va, o4.w, ao0.w);
        ar1.x = fmaf(vb, w4.x, ar1.x); ar1.y = fmaf(vb, w4.y, ar1.y);
        ar1.z = fmaf(vb, w4.z, ar1.z); ar1.w = fmaf(vb, w4.w, ar1.w);
        ao1.x = fmaf(vb, o4.x, ao1.x); ao1.y = fmaf(vb, o4.y, ao1.y);
        ao1.z = fmaf(vb, o4.z, ao1.z); ao1.w = fmaf(vb, o4.w, ao1.w);
    }
    float4 bb = *(const float4*)&sb[fq];
    int n0 = base + nl, n1 = base + nl + 32;
    if (n0 < N) {
        __half2 pa = __floats2half2_rn(ar0.x, ar0.y);
        __half2 pb = __floats2half2_rn(ar0.z, ar0.w);
        uint2 pk; pk.x = *(unsigned*)&pa; pk.y = *(unsigned*)&pb;
        *(uint2*)&A[(size_t)n0 * HID + fq] = pk;
        ao0.x += bb.x; ao0.y += bb.y; ao0.z += bb.z; ao0.w += bb.w;
        *(float4*)&C[(size_t)n0 * HID + fq] = ao0;
    }
    if (n1 < N) {
        __half2 pa = __floats2half2_rn(ar1.x, ar1.y);
        __half2 pb = __floats2half2_rn(ar1.z, ar1.w);
        uint2 pk; pk.x = *(unsigned*)&pa; pk.y = *(unsigned*)&pb;
        *(uint2*)&A[(size_t)n1 * HID + fq] = pk;
        ao1.x += bb.x; ao1.y += bb.y; ao1.z += bb.z; ao1.w += bb.w;
        *(float4*)&C[(size_t)n1 * HID + fq] = ao1;
    }
}

// ---------- rest of the deterministic partition build ----------

__global__ __launch_bounds__(256) void bucket_scan(
    int* __restrict__ cbb, int* __restrict__ btot, int NBLK)
{
    __shared__ int sc[256];
    size_t row = (size_t)blockIdx.x * NBLK;
    int t = threadIdx.x;
    int base = t * 4;
    int v[4]; int s = 0;
    #pragma unroll
    for (int j = 0; j < 4; ++j) { v[j] = (base + j < NBLK) ? cbb[row + base + j] : 0; s += v[j]; }
    sc[t] = s;
    __syncthreads();
    int acc = s;
    for (int off = 1; off < 256; off <<= 1) {
        int add = (t >= off) ? sc[t - off] : 0;
        __syncthreads();
        acc += add;
        sc[t] = acc;
        __syncthreads();
    }
    int run = acc - s;
    #pragma unroll
    for (int j = 0; j < 4; ++j) {
        if (base + j < NBLK) cbb[row + base + j] = run;
        run += v[j];
    }
    if (t == 255) btot[blockIdx.x] = acc;
}

__global__ __launch_bounds__(256) void btot_scan(
    const int* __restrict__ btot, int* __restrict__ bbase, int K)
{
    __shared__ int sc[256];
    int t = threadIdx.x;
    int base = t * 4;
    int v[4]; int s = 0;
    #pragma unroll
    for (int j = 0; j < 4; ++j) { v[j] = (base + j < K) ? btot[base + j] : 0; s += v[j]; }
    sc[t] = s;
    __syncthreads();
    int acc = s;
    for (int off = 1; off < 256; off <<= 1) {
        int add = (t >= off) ? sc[t - off] : 0;
        __syncthreads();
        acc += add;
        sc[t] = acc;
        __syncthreads();
    }
    int run = acc - s;
    #pragma unroll
    for (int j = 0; j < 4; ++j) {
        if (base + j < K) bbase[base + j] = run;
        run += v[j];
    }
    if (t == 255) bbase[K] = acc;
}

// partition: edges -> bucket-grouped staging; payload = {src | dloc<<17, ew}
__global__ __launch_bounds__(256) void partB(
    const int* __restrict__ src, const int* __restrict__ dst,
    const float* __restrict__ ew, const int* __restrict__ cbb,
    const int* __restrict__ bbase, int2* __restrict__ stg8,
    int E, int K, int NBLK)
{
    __shared__ int4 pay[EPB];       // 32 KB: {meta, ew, tgt, pad}
    __shared__ int h[KMAX2];
    __shared__ int lofs[KMAX2];
    __shared__ int gb[KMAX2];
    __shared__ int sc[256];
    int tid = threadIdx.x;
    for (int i = tid; i < K; i += 256) h[i] = 0;
    __syncthreads();

    int base = blockIdx.x * EPB;
    int es[EPT], ds[EPT]; float wsr[EPT];
    #pragma unroll
    for (int k = 0; k < EPT; ++k) {
        int e = base + k * 256 + tid;
        if (e < E) {
            es[k] = src[e]; ds[k] = dst[e]; wsr[k] = ew[e];
            atomicAdd(&h[ds[k] >> NB_SHIFT], 1);
        } else ds[k] = -1;
    }
    __syncthreads();

    int b0 = tid * 2;
    int v0 = (b0 < K) ? h[b0] : 0;
    int v1 = (b0 + 1 < K) ? h[b0 + 1] : 0;
    int s = v0 + v1;
    sc[tid] = s;
    __syncthreads();
    int acc = s;
    for (int off = 1; off < 256; off <<= 1) {
        int add = (tid >= off) ? sc[tid - off] : 0;
        __syncthreads();
        acc += add;
        sc[tid] = acc;
        __syncthreads();
    }
    int run = acc - s;
    if (b0 < K) lofs[b0] = run;
    if (b0 + 1 < K) lofs[b0 + 1] = run + v0;
    __syncthreads();

    for (int b = tid; b < K; b += 256) {
        gb[b] = bbase[b] + cbb[(size_t)b * NBLK + blockIdx.x];
        h[b] = lofs[b];
    }
    __syncthreads();

    #pragma unroll
    for (int k = 0; k < EPT; ++k) {
        if (ds[k] >= 0) {
            int b = ds[k] >> NB_SHIFT;
            int dloc = ds[k] & (NB_NODES - 1);
            int slot = atomicAdd(&h[b], 1);
            pay[slot] = make_int4(es[k] | (dloc << 17), __float_as_int(wsr[k]),
                                  gb[b] + slot - lofs[b], 0);
        }
    }
    __syncthreads();

    int tot = E - base; if (tot > EPB) tot = EPB;
    for (int i = tid; i < tot; i += 256) {
        int4 p = pay[i];
        stg8[p.z] = make_int2(p.x, p.y);
    }
}

// per bucket: counting-sort edges by dst node, LDS-staged single-pass
__global__ __launch_bounds__(512) void partC2(
    const int2* __restrict__ stg8, const int* __restrict__ bbase,
    int* __restrict__ rowptr, int2* __restrict__ perm, int N, int K)
{
    __shared__ int2 pe[PCAP];          // 47 KB edge staging
    __shared__ int hcnt[NB_NODES];
    __shared__ int hinc[NB_NODES];
    int b = blockIdx.x;
    int n0 = b << NB_SHIFT;
    int nTop = n0 + NB_NODES; if (nTop > N) nTop = N;
    int nloc = nTop - n0;
    int tid = threadIdx.x;
    if (tid < NB_NODES) hcnt[tid] = 0;
    int lo = bbase[b], hi = bbase[b + 1];
    int sz = hi - lo;
    bool fit = (sz <= PCAP);
    if (fit) {
        for (int i = tid; i < sz; i += 512) pe[i] = stg8[lo + i];
    }
    __syncthreads();
    if (fit) {
        for (int i = tid; i < sz; i += 512)
            atomicAdd(&hcnt[pe[i].x >> 17], 1);
    } else {
        for (int e = lo + tid; e < hi; e += 512)
            atomicAdd(&hcnt[stg8[e].x >> 17], 1);
    }
    __syncthreads();
    if (tid < NB_NODES) hinc[tid] = hcnt[tid];
    __syncthreads();
    for (int off = 1; off < NB_NODES; off <<= 1) {
        int v = (tid < NB_NODES && tid >= off) ? hinc[tid - off] : 0;
        __syncthreads();
        if (tid < NB_NODES) hinc[tid] += v;
        __syncthreads();
    }
    if (tid < nloc) {
        int excl = hinc[tid] - hcnt[tid];
        rowptr[n0 + tid] = lo + excl;
        hcnt[tid] = excl;               // reuse as cursor
    }
    if (b == K - 1 && tid == 0) rowptr[N] = hi;
    __syncthreads();
    if (fit) {
        for (int i = tid; i < sz; i += 512) {
            int2 p = pe[i];
            int pos = lo + atomicAdd(&hcnt[p.x >> 17], 1);
            perm[pos] = make_int2(p.x & 0x1FFFF, p.y);
        }
    } else {
        for (int e = lo + tid; e < hi; e += 512) {
            int2 p = stg8[e];
            int pos = lo + atomicAdd(&hcnt[p.x >> 17], 1);
            perm[pos] = make_int2(p.x & 0x1FFFF, p.y);
        }
    }
}

// ---------- gather-side aggregation: 8 lanes per node, no cross-lane reduce ----
// lane q of a node owns feature pair-columns [4q, 4q+4); each lane loops the
// node's full edge list (perm reads broadcast across the 8 lanes; gathers are
// 64 B contiguous per edge). 8 nodes per wave -> 8 independent chains/wave.
__global__ __launch_bounds__(256) void csr_agg(
    const int* __restrict__ rowptr, const int2* __restrict__ perm,
    const __half* __restrict__ A, float* __restrict__ out, int N)
{
    int gid = blockIdx.x * 256 + threadIdx.x;
    int n = gid >> 3;            // 8 threads per node
    if (n >= N) return;
    int q = threadIdx.x & 7;     // uint2 column within 32-half row
    int e0 = rowptr[n], e1 = rowptr[n + 1];
    const uint2* A2 = (const uint2*)A;   // row stride = 8 uint2
    float4 a0 = make_float4(0.f, 0.f, 0.f, 0.f);
    float4 a1 = make_float4(0.f, 0.f, 0.f, 0.f);
    int e = e0;
    for (; e + 1 < e1; e += 2) {
        int2 p0 = perm[e];
        int2 p1 = perm[e + 1];
        uint2 r0 = A2[(size_t)p0.x * 8 + q];
        uint2 r1 = A2[(size_t)p1.x * 8 + q];
        float w0 = __int_as_float(p0.y), w1 = __int_as_float(p1.y);
        float2 f01 = __half22float2(*(__half2*)&r0.x);
        float2 f23 = __half22float2(*(__half2*)&r0.y);
        float2 g01 = __half22float2(*(__half2*)&r1.x);
        float2 g23 = __half22float2(*(__half2*)&r1.y);
        a0.x = fmaf(f01.x, w0, a0.x); a0.y = fmaf(f01.y, w0, a0.y);
        a0.z = fmaf(f23.x, w0, a0.z); a0.w = fmaf(f23.y, w0, a0.w);
        a1.x = fmaf(g01.x, w1, a1.x); a1.y = fmaf(g01.y, w1, a1.y);
        a1.z = fmaf(g23.x, w1, a1.z); a1.w = fmaf(g23.y, w1, a1.w);
    }
    if (e < e1) {
        int2 p = perm[e];
        uint2 r = A2[(size_t)p.x * 8 + q];
        float w = __int_as_float(p.y);
        float2 f01 = __half22float2(*(__half2*)&r.x);
        float2 f23 = __half22float2(*(__half2*)&r.y);
        a0.x = fmaf(f01.x, w, a0.x); a0.y = fmaf(f01.y, w, a0.y);
        a0.z = fmaf(f23.x, w, a0.z); a0.w = fmaf(f23.y, w, a0.w);
    }
    a0.x += a1.x; a0.y += a1.y; a0.z += a1.z; a0.w += a1.w;
    float4* O4 = (float4*)out;
    size_t oi = (size_t)n * 8 + q;
    float4 o = O4[oi];
    o.x += a0.x; o.y += a0.y; o.z += a0.z; o.w += a0.w;
    O4[oi] = o;
}

// ---------- fused pool + MLP: one block per graph, batch sorted ----------
__global__ __launch_bounds__(256) void pool_mlp(
    const float* __restrict__ C, const int* __restrict__ batch, int N,
    const float* __restrict__ W1, const float* __restrict__ b1,
    const float* __restrict__ W2, const float* __restrict__ b2,
    const float* __restrict__ W3, const float* __restrict__ b3,
    float* __restrict__ out)
{
    int g = blockIdx.x;
    int tid = threadIdx.x;
    int lo, hi;
    {
        int l = 0, r = N;
        while (l < r) { int m = (l + r) >> 1; if (batch[m] < g) l = m + 1; else r = m; }
        lo = l;
        r = N;
        while (l < r) { int m = (l + r) >> 1; if (batch[m] < g + 1) l = m + 1; else r = m; }
        hi = l;
    }
    __shared__ float ssum[8][32];
    __shared__ float gvec[32];
    __shared__ float h1v[32];
    __shared__ float h2v[16];
    int f = tid & 31, seg = tid >> 5;
    float acc = 0.f;
    for (int n = lo + seg; n < hi; n += 8) {
        float v = C[(size_t)n * HID + f];
        acc += v > 0.f ? v : 0.f;
    }
    ssum[seg][f] = acc;
    __syncthreads();
    if (tid < 32) {
        float s = 0.f;
        #pragma unroll
        for (int k = 0; k < 8; ++k) s += ssum[k][tid];
        float c = (float)(hi - lo); c = c > 1.f ? c : 1.f;
        gvec[tid] = s / c;
    }
    __syncthreads();
    if (tid < 32) {
        float a = b1[tid];
        #pragma unroll
        for (int k = 0; k < 32; ++k) a = fmaf(gvec[k], W1[k * 32 + tid], a);
        h1v[tid] = a > 0.f ? a : 0.f;
    }
    __syncthreads();
    if (tid < 16) {
        float a = b2[tid];
        #pragma unroll
        for (int k = 0; k < 32; ++k) a = fmaf(h1v[k], W2[k * 16 + tid], a);
        h2v[tid] = a > 0.f ? a : 0.f;
    }
    __syncthreads();
    if (tid == 0) {
        float o = b3[0];
        #pragma unroll
        for (int k = 0; k < 16; ++k) o = fmaf(h2v[k], W3[k], o);
        out[g] = o;
    }
}

extern "C" void kernel_launch(void* const* d_in, const int* in_sizes, int n_in,
                              void* d_out, int out_size, void* d_ws, size_t ws_size,
                              hipStream_t stream) {
    const float* x     = (const float*)d_in[0];
    const int*   ei    = (const int*)d_in[1];
    const float* ew    = (const float*)d_in[2];
    const int*   batch = (const int*)d_in[3];
    const float* c1rw  = (const float*)d_in[4];
    const float* c1rb  = (const float*)d_in[5];
    const float* c1ow  = (const float*)d_in[6];
    const float* c2rw  = (const float*)d_in[7];
    const float* c2rb  = (const float*)d_in[8];
    const float* c2ow  = (const float*)d_in[9];
    const float* l1w   = (const float*)d_in[10];
    const float* l1b   = (const float*)d_in[11];
    const float* l2w   = (const float*)d_in[12];
    const float* l2b   = (const float*)d_in[13];
    const float* lw    = (const float*)d_in[14];
    const float* lb    = (const float*)d_in[15];

    int N = in_sizes[0] / FIN;      // 100000
    int E = in_sizes[2];            // 1600000
    const int* src = ei;
    const int* dst = ei + E;
    int K    = (N + NB_NODES - 1) >> NB_SHIFT;   // 391 buckets (256 nodes)
    int NBLK = (E + EPB - 1) / EPB;              // 782 edge blocks

    // ---- workspace layout (no aliasing: lin64 runs concurrently with build) ----
    char* ws = (char*)d_ws;
    size_t off = 0;
    auto alloc = [&](size_t nbytes) { void* p = ws + off; off += (nbytes + 255) & ~size_t(255); return p; };
    __half* A     = (__half*)alloc((size_t)N * HID * 2);        // 6.4 MB (fp16)
    float*  BC    = (float*) alloc((size_t)N * HID * 4);        // 12.8 MB
    int2*   perm  = (int2*)  alloc((size_t)E * 8);              // 12.8 MB
    int2*   stg8  = (int2*)  alloc((size_t)E * 8);              // 12.8 MB
    int*    cbb   = (int*)   alloc((size_t)K * NBLK * 4);       // 1.22 MB
    int*   rowptr = (int*)   alloc((size_t)(N + 1) * 4);
    int*   btot   = (int*)   alloc((size_t)KMAX2 * 4);
    int*   bbase  = (int*)   alloc((size_t)(KMAX2 + 1) * 4);

    int nb_node = (N + NT - 1) / NT;
    int nb_agg  = (int)(((long long)N * 8 + 255) / 256);   // 8 threads per node

    // fused: histogram (NBLK blocks) || conv1 linear (nb_node blocks)
    hist_lin64<<<NBLK + nb_node, 256, 0, stream>>>(
        dst, cbb, E, K, NBLK, x, c1rw, c1ow, c1rb, A, BC, N);
    // rest of partition build
    bucket_scan<<<K, 256, 0, stream>>>(cbb, btot, NBLK);
    btot_scan<<<1, 256, 0, stream>>>(btot, bbase, K);
    partB<<<NBLK, 256, 0, stream>>>(src, dst, ew, cbb, bbase, stg8, E, K, NBLK);
    partC2<<<K, 512, 0, stream>>>(stg8, bbase, rowptr, perm, N, K);

    // conv1 aggregation
    csr_agg<<<nb_agg, 256, 0, stream>>>(rowptr, perm, A, BC, N);
    // conv2 (relu fused into node_lin32 load; A overwritten with layer-2 rel-proj)
    node_lin32<<<nb_node, 256, 0, stream>>>(BC, c2rw, c2ow, c2rb, A, BC, N);
    csr_agg<<<nb_agg, 256, 0, stream>>>(rowptr, perm, A, BC, N);
    // fused pool + MLP
    pool_mlp<<<NGRAPH, 256, 0, stream>>>(BC, batch, N, l1w, l1b, l2w, l2b, lw, lb,
                                         (float*)d_out);
}